// Round 1
// baseline (103.706 us; speedup 1.0000x reference)
//
#include <hip/hip_runtime.h>
#include <cmath>

#define NK       10000
#define GROUP    2000
#define SEQ_L    256
#define FEAT_DIM 20000
#define NBATCH   16

__device__ __forceinline__ float4 lds_ld4(const float* p) {
    return *reinterpret_cast<const float4*>(p);
}

// ---------------------------------------------------------------------------
// Kernel A: dilated conv features (max + PPV) per (kernel n, batch b)
// grid = (40, 16), block = 256. One batch's padded x staged in LDS.
// ---------------------------------------------------------------------------
__launch_bounds__(256)
__global__ void rocket_feat(const float* __restrict__ x_enc,  // (16,256,3)
                            const float* __restrict__ Wk,     // (10000,3,9)
                            const float* __restrict__ bias,   // (10000,)
                            float* __restrict__ feat)         // (16,20000)
{
    __shared__ __align__(16) float xp[3 * 384];   // [c][t+64], zero-padded +-64

    const int b   = blockIdx.y;
    const int tid = threadIdx.x;

    // zero the padded buffer, then fill interior
    for (int i = tid; i < 3 * 384; i += 256) xp[i] = 0.f;
    __syncthreads();
    for (int e = tid; e < SEQ_L * 3; e += 256) {
        int l = e / 3;
        int c = e - l * 3;
        xp[c * 384 + 64 + l] = x_enc[b * (SEQ_L * 3) + e];  // x[b,l,c] -> xp[c][l+64]
    }
    __syncthreads();

    const int n = blockIdx.x * 256 + tid;
    if (n >= NK) return;

    const int gi = n / GROUP;        // dilation group 0..4
    const int d  = 1 << gi;          // 1,2,4,8,16

    float w[27];
#pragma unroll
    for (int j = 0; j < 27; ++j) w[j] = Wk[n * 27 + j];
    const float bs = bias[n];

    float mx  = -INFINITY;
    int   cnt = 0;

    if (d == 1) {
        for (int t0 = 0; t0 < SEQ_L; t0 += 4) {
            float s0 = bs, s1 = bs, s2 = bs, s3 = bs;
            const int base = t0 + 60;                 // t0+64-4*1, %4==0
#pragma unroll
            for (int c = 0; c < 3; ++c) {
                float xw[12];
                *(float4*)&xw[0] = lds_ld4(&xp[c * 384 + base]);
                *(float4*)&xw[4] = lds_ld4(&xp[c * 384 + base + 4]);
                *(float4*)&xw[8] = lds_ld4(&xp[c * 384 + base + 8]);
#pragma unroll
                for (int k = 0; k < 9; ++k) {
                    const float wk = w[c * 9 + k];
                    s0 = fmaf(xw[k],     wk, s0);
                    s1 = fmaf(xw[k + 1], wk, s1);
                    s2 = fmaf(xw[k + 2], wk, s2);
                    s3 = fmaf(xw[k + 3], wk, s3);
                }
            }
            mx = fmaxf(mx, fmaxf(fmaxf(s0, s1), fmaxf(s2, s3)));
            cnt += (s0 > 0.f) + (s1 > 0.f) + (s2 > 0.f) + (s3 > 0.f);
        }
    } else if (d == 2) {
        for (int t0 = 0; t0 < SEQ_L; t0 += 4) {
            float s0 = bs, s1 = bs, s2 = bs, s3 = bs;
            const int base = t0 + 56;                 // t0+64-8, %4==0
#pragma unroll
            for (int c = 0; c < 3; ++c) {
                float xw[20];
                *(float4*)&xw[0]  = lds_ld4(&xp[c * 384 + base]);
                *(float4*)&xw[4]  = lds_ld4(&xp[c * 384 + base + 4]);
                *(float4*)&xw[8]  = lds_ld4(&xp[c * 384 + base + 8]);
                *(float4*)&xw[12] = lds_ld4(&xp[c * 384 + base + 12]);
                *(float4*)&xw[16] = lds_ld4(&xp[c * 384 + base + 16]);
#pragma unroll
                for (int k = 0; k < 9; ++k) {
                    const float wk = w[c * 9 + k];
                    s0 = fmaf(xw[2 * k],     wk, s0);
                    s1 = fmaf(xw[2 * k + 1], wk, s1);
                    s2 = fmaf(xw[2 * k + 2], wk, s2);
                    s3 = fmaf(xw[2 * k + 3], wk, s3);
                }
            }
            mx = fmaxf(mx, fmaxf(fmaxf(s0, s1), fmaxf(s2, s3)));
            cnt += (s0 > 0.f) + (s1 > 0.f) + (s2 > 0.f) + (s3 > 0.f);
        }
    } else {
        // d in {4,8,16}: every tap window [base+k*d .. +3] is one aligned float4
        for (int t0 = 0; t0 < SEQ_L; t0 += 4) {
            float s0 = bs, s1 = bs, s2 = bs, s3 = bs;
            const int base = t0 + 64 - 4 * d;
#pragma unroll
            for (int c = 0; c < 3; ++c) {
#pragma unroll
                for (int k = 0; k < 9; ++k) {
                    const float4 xv = lds_ld4(&xp[c * 384 + base + k * d]);
                    const float  wk = w[c * 9 + k];
                    s0 = fmaf(xv.x, wk, s0);
                    s1 = fmaf(xv.y, wk, s1);
                    s2 = fmaf(xv.z, wk, s2);
                    s3 = fmaf(xv.w, wk, s3);
                }
            }
            mx = fmaxf(mx, fmaxf(fmaxf(s0, s1), fmaxf(s2, s3)));
            cnt += (s0 > 0.f) + (s1 > 0.f) + (s2 > 0.f) + (s3 > 0.f);
        }
    }

    const int j = n - gi * GROUP;
    feat[b * FEAT_DIM + gi * 4000 + j]        = mx;
    feat[b * FEAT_DIM + gi * 4000 + 2000 + j] = (float)cnt * (1.0f / 256.0f);
}

// ---------------------------------------------------------------------------
// Kernel B: per-feature BN folded to affine: feat_n = feat*g + h
// ---------------------------------------------------------------------------
__launch_bounds__(256)
__global__ void bn_stats(const float* __restrict__ feat,
                         const float* __restrict__ gamma,
                         const float* __restrict__ beta,
                         float* __restrict__ g, float* __restrict__ h)
{
    const int f = blockIdx.x * 256 + threadIdx.x;
    if (f >= FEAT_DIM) return;
    float s = 0.f, ss = 0.f;
#pragma unroll
    for (int b = 0; b < NBATCH; ++b) {
        const float v = feat[b * FEAT_DIM + f];
        s += v;
        ss += v * v;
    }
    const float mu  = s * (1.f / NBATCH);
    const float var = ss * (1.f / NBATCH) - mu * mu;
    const float gg  = gamma[f] * rsqrtf(var + 1e-5f);
    g[f] = gg;
    h[f] = beta[f] - mu * gg;
}

// ---------------------------------------------------------------------------
// Kernel C: out[b,c] = sum_f (feat[b,f]*g[f]+h[f]) * linW[f,c] + linB[c]
// one block per output element; fixed-order deterministic reduction
// ---------------------------------------------------------------------------
__launch_bounds__(256)
__global__ void out_gemv(const float* __restrict__ feat,
                         const float* __restrict__ g,
                         const float* __restrict__ h,
                         const float* __restrict__ linW,  // (20000,10)
                         const float* __restrict__ linB,  // (10,)
                         float* __restrict__ out)         // (16,10)
{
    const int blk = blockIdx.x;            // 0..159
    const int b   = blk / 10;
    const int c   = blk - b * 10;
    const int tid = threadIdx.x;

    float acc = 0.f;
    for (int f = tid; f < FEAT_DIM; f += 256) {
        acc += (feat[b * FEAT_DIM + f] * g[f] + h[f]) * linW[f * 10 + c];
    }
#pragma unroll
    for (int o = 32; o > 0; o >>= 1) acc += __shfl_down(acc, o, 64);

    __shared__ float red[4];
    if ((tid & 63) == 0) red[tid >> 6] = acc;
    __syncthreads();
    if (tid == 0) out[blk] = red[0] + red[1] + red[2] + red[3] + linB[c];
}

// ---------------------------------------------------------------------------
extern "C" void kernel_launch(void* const* d_in, const int* in_sizes, int n_in,
                              void* d_out, int out_size, void* d_ws, size_t ws_size,
                              hipStream_t stream) {
    const float* x     = (const float*)d_in[0];
    const float* Wk    = (const float*)d_in[1];
    const float* bias  = (const float*)d_in[2];
    const float* gamma = (const float*)d_in[3];
    const float* beta  = (const float*)d_in[4];
    const float* linW  = (const float*)d_in[5];
    const float* linB  = (const float*)d_in[6];
    float* out = (float*)d_out;

    float* feat = (float*)d_ws;                    // 16*20000 floats
    float* g    = feat + NBATCH * FEAT_DIM;        // 20000 floats
    float* h    = g + FEAT_DIM;                    // 20000 floats

    rocket_feat<<<dim3(40, 16), 256, 0, stream>>>(x, Wk, bias, feat);
    bn_stats<<<dim3((FEAT_DIM + 255) / 256), 256, 0, stream>>>(feat, gamma, beta, g, h);
    out_gemv<<<dim3(160), 256, 0, stream>>>(feat, g, h, linW, linB, out);
}

// Round 2
// 87.567 us; speedup vs baseline: 1.1843x; 1.1843x over previous
//
#include <hip/hip_runtime.h>
#include <cmath>

#define NK       10000
#define GROUP    2000
#define SEQ_L    256
#define FEAT_DIM 20000
#define NBATCH   16
#define XPAD_C   384           // 64 zeros | 256 samples | 64 zeros

// ---------------------------------------------------------------------------
// Kernel P: build zero-padded x: xpad[b][c][384], xpad[b][c][64+l] = x[b,l,c]
// ---------------------------------------------------------------------------
__launch_bounds__(256)
__global__ void prepad(const float* __restrict__ x_enc, float* __restrict__ xpad)
{
    const int b   = blockIdx.x;
    const int tid = threadIdx.x;
    for (int i = tid; i < 3 * XPAD_C; i += 256) xpad[b * (3 * XPAD_C) + i] = 0.f;
    __syncthreads();
    for (int e = tid; e < SEQ_L * 3; e += 256) {
        const int l = e / 3;
        const int c = e - l * 3;
        xpad[b * (3 * XPAD_C) + c * XPAD_C + 64 + l] = x_enc[b * (SEQ_L * 3) + e];
    }
}

// ---------------------------------------------------------------------------
// Kernel A: dilated conv features. 1 wave per block; each thread owns TWO
// kernels (j and j+1000) of one dilation group; x read via wave-uniform
// loads from the padded buffer (SMEM/L1 pipe, zero LDS traffic).
// grid = (5 groups * 16 subblocks, 16 batches), block = 64.
// ---------------------------------------------------------------------------
__launch_bounds__(64)
__global__ void rocket_feat(const float* __restrict__ xpad,   // (16,3,384)
                            const float* __restrict__ Wk,     // (10000,3,9)
                            const float* __restrict__ bias,   // (10000,)
                            float* __restrict__ feat)         // (16,20000)
{
    const int gi = blockIdx.x >> 4;          // dilation group 0..4
    const int sb = blockIdx.x & 15;          // sub-block 0..15
    const int b  = blockIdx.y;
    const int d  = 1 << gi;
    const int j  = sb * 64 + threadIdx.x;    // 0..1023 (active if <1000)
    const bool act = (j < 1000);
    const int jj = act ? j : 0;

    const float* __restrict__ xb = xpad + b * (3 * XPAD_C);

    const int n0 = gi * GROUP + jj;
    const int n1 = n0 + 1000;

    float w0[27], w1[27];
#pragma unroll
    for (int q = 0; q < 27; ++q) { w0[q] = Wk[n0 * 27 + q]; w1[q] = Wk[n1 * 27 + q]; }
    const float bs0 = bias[n0];
    const float bs1 = bias[n1];

    float mx0 = -INFINITY, mx1 = -INFINITY;
    int cnt0 = 0, cnt1 = 0;

    if (d == 1) {
        for (int t0 = 0; t0 < SEQ_L; t0 += 4) {
            float a0 = bs0, a1 = bs0, a2 = bs0, a3 = bs0;
            float c0 = bs1, c1 = bs1, c2 = bs1, c3 = bs1;
            const int base = t0 + 60;
#pragma unroll
            for (int c = 0; c < 3; ++c) {
                const float* xc = xb + c * XPAD_C + base;
                float xw[12];
                *(float4*)&xw[0] = *(const float4*)(xc);
                *(float4*)&xw[4] = *(const float4*)(xc + 4);
                *(float4*)&xw[8] = *(const float4*)(xc + 8);
#pragma unroll
                for (int k = 0; k < 9; ++k) {
                    const float u = w0[c * 9 + k], v = w1[c * 9 + k];
                    a0 = fmaf(xw[k],     u, a0);  c0 = fmaf(xw[k],     v, c0);
                    a1 = fmaf(xw[k + 1], u, a1);  c1 = fmaf(xw[k + 1], v, c1);
                    a2 = fmaf(xw[k + 2], u, a2);  c2 = fmaf(xw[k + 2], v, c2);
                    a3 = fmaf(xw[k + 3], u, a3);  c3 = fmaf(xw[k + 3], v, c3);
                }
            }
            mx0 = fmaxf(mx0, fmaxf(fmaxf(a0, a1), fmaxf(a2, a3)));
            mx1 = fmaxf(mx1, fmaxf(fmaxf(c0, c1), fmaxf(c2, c3)));
            cnt0 += (a0 > 0.f) + (a1 > 0.f) + (a2 > 0.f) + (a3 > 0.f);
            cnt1 += (c0 > 0.f) + (c1 > 0.f) + (c2 > 0.f) + (c3 > 0.f);
        }
    } else if (d == 2) {
        for (int t0 = 0; t0 < SEQ_L; t0 += 4) {
            float a0 = bs0, a1 = bs0, a2 = bs0, a3 = bs0;
            float c0 = bs1, c1 = bs1, c2 = bs1, c3 = bs1;
            const int base = t0 + 56;
#pragma unroll
            for (int c = 0; c < 3; ++c) {
                const float* xc = xb + c * XPAD_C + base;
                float xw[20];
                *(float4*)&xw[0]  = *(const float4*)(xc);
                *(float4*)&xw[4]  = *(const float4*)(xc + 4);
                *(float4*)&xw[8]  = *(const float4*)(xc + 8);
                *(float4*)&xw[12] = *(const float4*)(xc + 12);
                *(float4*)&xw[16] = *(const float4*)(xc + 16);
#pragma unroll
                for (int k = 0; k < 9; ++k) {
                    const float u = w0[c * 9 + k], v = w1[c * 9 + k];
                    a0 = fmaf(xw[2 * k],     u, a0);  c0 = fmaf(xw[2 * k],     v, c0);
                    a1 = fmaf(xw[2 * k + 1], u, a1);  c1 = fmaf(xw[2 * k + 1], v, c1);
                    a2 = fmaf(xw[2 * k + 2], u, a2);  c2 = fmaf(xw[2 * k + 2], v, c2);
                    a3 = fmaf(xw[2 * k + 3], u, a3);  c3 = fmaf(xw[2 * k + 3], v, c3);
                }
            }
            mx0 = fmaxf(mx0, fmaxf(fmaxf(a0, a1), fmaxf(a2, a3)));
            mx1 = fmaxf(mx1, fmaxf(fmaxf(c0, c1), fmaxf(c2, c3)));
            cnt0 += (a0 > 0.f) + (a1 > 0.f) + (a2 > 0.f) + (a3 > 0.f);
            cnt1 += (c0 > 0.f) + (c1 > 0.f) + (c2 > 0.f) + (c3 > 0.f);
        }
    } else {
        for (int t0 = 0; t0 < SEQ_L; t0 += 4) {
            float a0 = bs0, a1 = bs0, a2 = bs0, a3 = bs0;
            float c0 = bs1, c1 = bs1, c2 = bs1, c3 = bs1;
            const int base = t0 + 64 - 4 * d;
#pragma unroll
            for (int c = 0; c < 3; ++c) {
                const float* xc = xb + c * XPAD_C + base;
#pragma unroll
                for (int k = 0; k < 9; ++k) {
                    const float4 xv = *(const float4*)(xc + k * d);
                    const float u = w0[c * 9 + k], v = w1[c * 9 + k];
                    a0 = fmaf(xv.x, u, a0);  c0 = fmaf(xv.x, v, c0);
                    a1 = fmaf(xv.y, u, a1);  c1 = fmaf(xv.y, v, c1);
                    a2 = fmaf(xv.z, u, a2);  c2 = fmaf(xv.z, v, c2);
                    a3 = fmaf(xv.w, u, a3);  c3 = fmaf(xv.w, v, c3);
                }
            }
            mx0 = fmaxf(mx0, fmaxf(fmaxf(a0, a1), fmaxf(a2, a3)));
            mx1 = fmaxf(mx1, fmaxf(fmaxf(c0, c1), fmaxf(c2, c3)));
            cnt0 += (a0 > 0.f) + (a1 > 0.f) + (a2 > 0.f) + (a3 > 0.f);
            cnt1 += (c0 > 0.f) + (c1 > 0.f) + (c2 > 0.f) + (c3 > 0.f);
        }
    }

    if (act) {
        float* fb = feat + b * FEAT_DIM + gi * 4000;
        fb[j]               = mx0;
        fb[j + 1000]        = mx1;
        fb[2000 + j]        = (float)cnt0 * (1.0f / 256.0f);
        fb[2000 + j + 1000] = (float)cnt1 * (1.0f / 256.0f);
    }
}

// ---------------------------------------------------------------------------
// Kernel B: fold BN into affine feat_n = feat*g + h
// ---------------------------------------------------------------------------
__launch_bounds__(256)
__global__ void bn_stats(const float* __restrict__ feat,
                         const float* __restrict__ gamma,
                         const float* __restrict__ beta,
                         float* __restrict__ g, float* __restrict__ h)
{
    const int f = blockIdx.x * 256 + threadIdx.x;
    if (f >= FEAT_DIM) return;
    float s = 0.f, ss = 0.f;
#pragma unroll
    for (int b = 0; b < NBATCH; ++b) {
        const float v = feat[b * FEAT_DIM + f];
        s += v;
        ss += v * v;
    }
    const float mu  = s * (1.f / NBATCH);
    const float var = ss * (1.f / NBATCH) - mu * mu;
    const float gg  = gamma[f] * rsqrtf(var + 1e-5f);
    g[f] = gg;
    h[f] = beta[f] - mu * gg;
}

// ---------------------------------------------------------------------------
// Kernel C: out[b,:] = sum_f (feat*g+h) * linW[f,:] + linB. 1 block per batch.
// ---------------------------------------------------------------------------
__launch_bounds__(256)
__global__ void out_gemv(const float* __restrict__ feat,
                         const float* __restrict__ g,
                         const float* __restrict__ h,
                         const float* __restrict__ linW,  // (20000,10)
                         const float* __restrict__ linB,  // (10,)
                         float* __restrict__ out)         // (16,10)
{
    const int b   = blockIdx.x;
    const int tid = threadIdx.x;

    float acc[10];
#pragma unroll
    for (int c = 0; c < 10; ++c) acc[c] = 0.f;

    for (int f = tid; f < FEAT_DIM; f += 256) {
        const float t = fmaf(feat[b * FEAT_DIM + f], g[f], h[f]);
#pragma unroll
        for (int c = 0; c < 10; ++c) acc[c] = fmaf(t, linW[f * 10 + c], acc[c]);
    }

#pragma unroll
    for (int c = 0; c < 10; ++c)
#pragma unroll
        for (int o = 32; o > 0; o >>= 1) acc[c] += __shfl_down(acc[c], o, 64);

    __shared__ float red[4][10];
    if ((tid & 63) == 0) {
#pragma unroll
        for (int c = 0; c < 10; ++c) red[tid >> 6][c] = acc[c];
    }
    __syncthreads();
    if (tid < 10)
        out[b * 10 + tid] = red[0][tid] + red[1][tid] + red[2][tid] + red[3][tid] + linB[tid];
}

// ---------------------------------------------------------------------------
extern "C" void kernel_launch(void* const* d_in, const int* in_sizes, int n_in,
                              void* d_out, int out_size, void* d_ws, size_t ws_size,
                              hipStream_t stream) {
    const float* x     = (const float*)d_in[0];
    const float* Wk    = (const float*)d_in[1];
    const float* bias  = (const float*)d_in[2];
    const float* gamma = (const float*)d_in[3];
    const float* beta  = (const float*)d_in[4];
    const float* linW  = (const float*)d_in[5];
    const float* linB  = (const float*)d_in[6];
    float* out = (float*)d_out;

    float* feat = (float*)d_ws;                    // 16*20000
    float* g    = feat + NBATCH * FEAT_DIM;        // 20000
    float* h    = g + FEAT_DIM;                    // 20000
    float* xpad = h + FEAT_DIM;                    // 16*3*384

    prepad<<<dim3(NBATCH), 256, 0, stream>>>(x, xpad);
    rocket_feat<<<dim3(80, NBATCH), 64, 0, stream>>>(xpad, Wk, bias, feat);
    bn_stats<<<dim3((FEAT_DIM + 255) / 256), 256, 0, stream>>>(feat, gamma, beta, g, h);
    out_gemv<<<dim3(NBATCH), 256, 0, stream>>>(feat, g, h, linW, linB, out);
}

// Round 3
// 87.301 us; speedup vs baseline: 1.1879x; 1.0031x over previous
//
#include <hip/hip_runtime.h>
#include <cmath>

#define NK       10000
#define GROUP    2000
#define SEQ_L    256
#define FEAT_DIM 20000
#define NBATCH   16
#define XPAD_C   384           // 64 zeros | 256 samples | 64 zeros

// ---------------------------------------------------------------------------
// Kernel P: build zero-padded x: xpad[b][c][384], xpad[b][c][64+l] = x[b,l,c]
// ---------------------------------------------------------------------------
__launch_bounds__(256)
__global__ void prepad(const float* __restrict__ x_enc, float* __restrict__ xpad)
{
    const int b   = blockIdx.x;
    const int tid = threadIdx.x;
    for (int i = tid; i < 3 * XPAD_C; i += 256) xpad[b * (3 * XPAD_C) + i] = 0.f;
    __syncthreads();
    for (int e = tid; e < SEQ_L * 3; e += 256) {
        const int l = e / 3;
        const int c = e - l * 3;
        xpad[b * (3 * XPAD_C) + c * XPAD_C + 64 + l] = x_enc[b * (SEQ_L * 3) + e];
    }
}

// ---------------------------------------------------------------------------
// Kernel A: dilated conv features. Block = 256 (4 waves); each wave computes
// the SAME 64 kernel-pairs over a DIFFERENT quarter of the 256 positions;
// 4 KB LDS combine at the end. x read via wave-uniform loads (scalar/L1).
// grid = (5 groups * 16 subblocks, 16 batches).
// ---------------------------------------------------------------------------
__launch_bounds__(256)
__global__ void rocket_feat(const float* __restrict__ xpad,   // (16,3,384)
                            const float* __restrict__ Wk,     // (10000,3,9)
                            const float* __restrict__ bias,    // (10000,)
                            float* __restrict__ feat)          // (16,20000)
{
    const int gi   = blockIdx.x >> 4;        // dilation group 0..4
    const int sb   = blockIdx.x & 15;        // sub-block 0..15
    const int b    = blockIdx.y;
    const int d    = 1 << gi;
    const int tid  = threadIdx.x;
    const int wv   = tid >> 6;               // wave 0..3 -> position chunk
    const int lane = tid & 63;
    const int j    = sb * 64 + lane;         // kernel index within group half
    const bool act = (j < 1000);
    const int jj   = act ? j : 0;

    const float* __restrict__ xb = xpad + b * (3 * XPAD_C);

    const int n0 = gi * GROUP + jj;
    const int n1 = n0 + 1000;

    float w0[27], w1[27];
#pragma unroll
    for (int q = 0; q < 27; ++q) { w0[q] = Wk[n0 * 27 + q]; w1[q] = Wk[n1 * 27 + q]; }
    const float bs0 = bias[n0];
    const float bs1 = bias[n1];

    float mx0 = -INFINITY, mx1 = -INFINITY;
    int cnt0 = 0, cnt1 = 0;

    const int tlo = wv * 64;
    const int thi = tlo + 64;

    if (d == 1) {
        for (int t0 = tlo; t0 < thi; t0 += 4) {
            float a0 = bs0, a1 = bs0, a2 = bs0, a3 = bs0;
            float c0 = bs1, c1 = bs1, c2 = bs1, c3 = bs1;
            const int base = t0 + 60;
#pragma unroll
            for (int c = 0; c < 3; ++c) {
                const float* xc = xb + c * XPAD_C + base;
                float xw[12];
                *(float4*)&xw[0] = *(const float4*)(xc);
                *(float4*)&xw[4] = *(const float4*)(xc + 4);
                *(float4*)&xw[8] = *(const float4*)(xc + 8);
#pragma unroll
                for (int k = 0; k < 9; ++k) {
                    const float u = w0[c * 9 + k], v = w1[c * 9 + k];
                    a0 = fmaf(xw[k],     u, a0);  c0 = fmaf(xw[k],     v, c0);
                    a1 = fmaf(xw[k + 1], u, a1);  c1 = fmaf(xw[k + 1], v, c1);
                    a2 = fmaf(xw[k + 2], u, a2);  c2 = fmaf(xw[k + 2], v, c2);
                    a3 = fmaf(xw[k + 3], u, a3);  c3 = fmaf(xw[k + 3], v, c3);
                }
            }
            mx0 = fmaxf(mx0, fmaxf(fmaxf(a0, a1), fmaxf(a2, a3)));
            mx1 = fmaxf(mx1, fmaxf(fmaxf(c0, c1), fmaxf(c2, c3)));
            cnt0 += (a0 > 0.f) + (a1 > 0.f) + (a2 > 0.f) + (a3 > 0.f);
            cnt1 += (c0 > 0.f) + (c1 > 0.f) + (c2 > 0.f) + (c3 > 0.f);
        }
    } else if (d == 2) {
        for (int t0 = tlo; t0 < thi; t0 += 4) {
            float a0 = bs0, a1 = bs0, a2 = bs0, a3 = bs0;
            float c0 = bs1, c1 = bs1, c2 = bs1, c3 = bs1;
            const int base = t0 + 56;
#pragma unroll
            for (int c = 0; c < 3; ++c) {
                const float* xc = xb + c * XPAD_C + base;
                float xw[20];
                *(float4*)&xw[0]  = *(const float4*)(xc);
                *(float4*)&xw[4]  = *(const float4*)(xc + 4);
                *(float4*)&xw[8]  = *(const float4*)(xc + 8);
                *(float4*)&xw[12] = *(const float4*)(xc + 12);
                *(float4*)&xw[16] = *(const float4*)(xc + 16);
#pragma unroll
                for (int k = 0; k < 9; ++k) {
                    const float u = w0[c * 9 + k], v = w1[c * 9 + k];
                    a0 = fmaf(xw[2 * k],     u, a0);  c0 = fmaf(xw[2 * k],     v, c0);
                    a1 = fmaf(xw[2 * k + 1], u, a1);  c1 = fmaf(xw[2 * k + 1], v, c1);
                    a2 = fmaf(xw[2 * k + 2], u, a2);  c2 = fmaf(xw[2 * k + 2], v, c2);
                    a3 = fmaf(xw[2 * k + 3], u, a3);  c3 = fmaf(xw[2 * k + 3], v, c3);
                }
            }
            mx0 = fmaxf(mx0, fmaxf(fmaxf(a0, a1), fmaxf(a2, a3)));
            mx1 = fmaxf(mx1, fmaxf(fmaxf(c0, c1), fmaxf(c2, c3)));
            cnt0 += (a0 > 0.f) + (a1 > 0.f) + (a2 > 0.f) + (a3 > 0.f);
            cnt1 += (c0 > 0.f) + (c1 > 0.f) + (c2 > 0.f) + (c3 > 0.f);
        }
    } else {
        for (int t0 = tlo; t0 < thi; t0 += 4) {
            float a0 = bs0, a1 = bs0, a2 = bs0, a3 = bs0;
            float c0 = bs1, c1 = bs1, c2 = bs1, c3 = bs1;
            const int base = t0 + 64 - 4 * d;
#pragma unroll
            for (int c = 0; c < 3; ++c) {
                const float* xc = xb + c * XPAD_C + base;
#pragma unroll
                for (int k = 0; k < 9; ++k) {
                    const float4 xv = *(const float4*)(xc + k * d);
                    const float u = w0[c * 9 + k], v = w1[c * 9 + k];
                    a0 = fmaf(xv.x, u, a0);  c0 = fmaf(xv.x, v, c0);
                    a1 = fmaf(xv.y, u, a1);  c1 = fmaf(xv.y, v, c1);
                    a2 = fmaf(xv.z, u, a2);  c2 = fmaf(xv.z, v, c2);
                    a3 = fmaf(xv.w, u, a3);  c3 = fmaf(xv.w, v, c3);
                }
            }
            mx0 = fmaxf(mx0, fmaxf(fmaxf(a0, a1), fmaxf(a2, a3)));
            mx1 = fmaxf(mx1, fmaxf(fmaxf(c0, c1), fmaxf(c2, c3)));
            cnt0 += (a0 > 0.f) + (a1 > 0.f) + (a2 > 0.f) + (a3 > 0.f);
            cnt1 += (c0 > 0.f) + (c1 > 0.f) + (c2 > 0.f) + (c3 > 0.f);
        }
    }

    // combine the 4 position-chunks across waves
    __shared__ float4 red[4][64];
    red[wv][lane] = make_float4(mx0, mx1, (float)cnt0, (float)cnt1);
    __syncthreads();

    if (wv == 0 && act) {
        const float4 r0 = red[0][lane], r1 = red[1][lane],
                     r2 = red[2][lane], r3 = red[3][lane];
        const float fmx0 = fmaxf(fmaxf(r0.x, r1.x), fmaxf(r2.x, r3.x));
        const float fmx1 = fmaxf(fmaxf(r0.y, r1.y), fmaxf(r2.y, r3.y));
        const float fc0  = r0.z + r1.z + r2.z + r3.z;
        const float fc1  = r0.w + r1.w + r2.w + r3.w;
        float* fb = feat + b * FEAT_DIM + gi * 4000;
        fb[j]               = fmx0;
        fb[j + 1000]        = fmx1;
        fb[2000 + j]        = fc0 * (1.0f / 256.0f);
        fb[2000 + j + 1000] = fc1 * (1.0f / 256.0f);
    }
}

// ---------------------------------------------------------------------------
// Kernel B: fold BN into affine feat_n = feat*g + h
// ---------------------------------------------------------------------------
__launch_bounds__(256)
__global__ void bn_stats(const float* __restrict__ feat,
                         const float* __restrict__ gamma,
                         const float* __restrict__ beta,
                         float* __restrict__ g, float* __restrict__ h)
{
    const int f = blockIdx.x * 256 + threadIdx.x;
    if (f >= FEAT_DIM) return;
    float s = 0.f, ss = 0.f;
#pragma unroll
    for (int b = 0; b < NBATCH; ++b) {
        const float v = feat[b * FEAT_DIM + f];
        s += v;
        ss += v * v;
    }
    const float mu  = s * (1.f / NBATCH);
    const float var = ss * (1.f / NBATCH) - mu * mu;
    const float gg  = gamma[f] * rsqrtf(var + 1e-5f);
    g[f] = gg;
    h[f] = beta[f] - mu * gg;
}

// ---------------------------------------------------------------------------
// Kernel C1: partial GEMV. grid (16 slices, 16 batches); each block reduces
// 1250 features into partial[(b*16+slice)*10 + c].
// ---------------------------------------------------------------------------
__launch_bounds__(256)
__global__ void gemv_partial(const float* __restrict__ feat,
                             const float* __restrict__ g,
                             const float* __restrict__ h,
                             const float* __restrict__ linW,  // (20000,10)
                             float* __restrict__ partial)     // (16,16,10)
{
    const int slice = blockIdx.x;
    const int b     = blockIdx.y;
    const int tid   = threadIdx.x;
    const int f0    = slice * 1250;
    const int f1    = f0 + 1250;

    float acc[10];
#pragma unroll
    for (int c = 0; c < 10; ++c) acc[c] = 0.f;

    for (int f = f0 + tid; f < f1; f += 256) {
        const float t = fmaf(feat[b * FEAT_DIM + f], g[f], h[f]);
#pragma unroll
        for (int c = 0; c < 10; ++c) acc[c] = fmaf(t, linW[f * 10 + c], acc[c]);
    }

#pragma unroll
    for (int c = 0; c < 10; ++c)
#pragma unroll
        for (int o = 32; o > 0; o >>= 1) acc[c] += __shfl_down(acc[c], o, 64);

    __shared__ float red[4][10];
    if ((tid & 63) == 0) {
#pragma unroll
        for (int c = 0; c < 10; ++c) red[tid >> 6][c] = acc[c];
    }
    __syncthreads();
    if (tid < 10)
        partial[(b * 16 + slice) * 10 + tid] =
            red[0][tid] + red[1][tid] + red[2][tid] + red[3][tid];
}

// ---------------------------------------------------------------------------
// Kernel C2: final reduce over slices + bias. 1 block, 160 threads.
// ---------------------------------------------------------------------------
__launch_bounds__(160)
__global__ void gemv_final(const float* __restrict__ partial,
                           const float* __restrict__ linB,
                           float* __restrict__ out)
{
    const int tid = threadIdx.x;       // 0..159
    const int b   = tid / 10;
    const int c   = tid - b * 10;
    float s = linB[c];
#pragma unroll
    for (int sl = 0; sl < 16; ++sl) s += partial[(b * 16 + sl) * 10 + c];
    out[tid] = s;
}

// ---------------------------------------------------------------------------
extern "C" void kernel_launch(void* const* d_in, const int* in_sizes, int n_in,
                              void* d_out, int out_size, void* d_ws, size_t ws_size,
                              hipStream_t stream) {
    const float* x     = (const float*)d_in[0];
    const float* Wk    = (const float*)d_in[1];
    const float* bias  = (const float*)d_in[2];
    const float* gamma = (const float*)d_in[3];
    const float* beta  = (const float*)d_in[4];
    const float* linW  = (const float*)d_in[5];
    const float* linB  = (const float*)d_in[6];
    float* out = (float*)d_out;

    float* feat    = (float*)d_ws;                     // 16*20000
    float* g       = feat + NBATCH * FEAT_DIM;         // 20000
    float* h       = g + FEAT_DIM;                     // 20000
    float* xpad    = h + FEAT_DIM;                     // 16*3*384
    float* partial = xpad + NBATCH * 3 * XPAD_C;       // 16*16*10

    prepad<<<dim3(NBATCH), 256, 0, stream>>>(x, xpad);
    rocket_feat<<<dim3(80, NBATCH), 256, 0, stream>>>(xpad, Wk, bias, feat);
    bn_stats<<<dim3((FEAT_DIM + 255) / 256), 256, 0, stream>>>(feat, gamma, beta, g, h);
    gemv_partial<<<dim3(16, NBATCH), 256, 0, stream>>>(feat, g, h, linW, partial);
    gemv_final<<<dim3(1), 160, 0, stream>>>(partial, linB, out);
}

// Round 4
// 68.850 us; speedup vs baseline: 1.5063x; 1.2680x over previous
//
#include <hip/hip_runtime.h>
#include <cmath>

#define NK       10000
#define GROUP    2000
#define SEQ_L    256
#define FEAT_DIM 20000
#define NBATCH   16
#define XPAD_C   384           // 64 zeros | 256 samples | 64 zeros

// ---------------------------------------------------------------------------
// Kernel P: build zero-padded x: xpad[b][c][384], xpad[b][c][64+l] = x[b,l,c]
// ---------------------------------------------------------------------------
__launch_bounds__(256)
__global__ void prepad(const float* __restrict__ x_enc, float* __restrict__ xpad)
{
    const int b   = blockIdx.x;
    const int tid = threadIdx.x;
    for (int i = tid; i < 3 * XPAD_C; i += 256) xpad[b * (3 * XPAD_C) + i] = 0.f;
    __syncthreads();
    for (int e = tid; e < SEQ_L * 3; e += 256) {
        const int l = e / 3;
        const int c = e - l * 3;
        xpad[b * (3 * XPAD_C) + c * XPAD_C + 64 + l] = x_enc[b * (SEQ_L * 3) + e];
    }
}

// ---------------------------------------------------------------------------
// Kernel A: dilated conv features. Block = 256 (4 waves); wave w handles
// position chunk [64w, 64w+64). The chunk index goes through
// readfirstlane so the compiler sees all x addresses as UNIFORM and keeps
// them on the scalar (s_load) path — this is the round-2 instruction mix
// at 4x the wave count. 4 KB LDS combine at the end.
// grid = (5 groups * 16 subblocks, 16 batches).
// ---------------------------------------------------------------------------
__launch_bounds__(256)
__global__ void rocket_feat(const float* __restrict__ xpad,   // (16,3,384)
                            const float* __restrict__ Wk,     // (10000,3,9)
                            const float* __restrict__ bias,   // (10000,)
                            float* __restrict__ feat)         // (16,20000)
{
    const int gi   = blockIdx.x >> 4;        // dilation group 0..4
    const int sb   = blockIdx.x & 15;        // sub-block 0..15
    const int b    = blockIdx.y;
    const int d    = 1 << gi;
    const int tid  = threadIdx.x;
    const int lane = tid & 63;
    // wave-uniform chunk index, FORCED uniform for the divergence analysis
    const int wv   = __builtin_amdgcn_readfirstlane(tid >> 6);   // 0..3
    const int j    = sb * 64 + lane;         // kernel index within group half
    const bool act = (j < 1000);
    const int jj   = act ? j : 0;

    const float* __restrict__ xb = xpad + b * (3 * XPAD_C);

    const int n0 = gi * GROUP + jj;
    const int n1 = n0 + 1000;

    float w0[27], w1[27];
#pragma unroll
    for (int q = 0; q < 27; ++q) { w0[q] = Wk[n0 * 27 + q]; w1[q] = Wk[n1 * 27 + q]; }
    const float bs0 = bias[n0];
    const float bs1 = bias[n1];

    float mx0 = -INFINITY, mx1 = -INFINITY;
    int cnt0 = 0, cnt1 = 0;

    const int tlo = wv * 64;                 // uniform
    const int thi = tlo + 64;

    if (d == 1) {
        for (int t0 = tlo; t0 < thi; t0 += 4) {
            float a0 = bs0, a1 = bs0, a2 = bs0, a3 = bs0;
            float c0 = bs1, c1 = bs1, c2 = bs1, c3 = bs1;
            const int base = t0 + 60;
#pragma unroll
            for (int c = 0; c < 3; ++c) {
                const float* xc = xb + c * XPAD_C + base;
                float xw[12];
                *(float4*)&xw[0] = *(const float4*)(xc);
                *(float4*)&xw[4] = *(const float4*)(xc + 4);
                *(float4*)&xw[8] = *(const float4*)(xc + 8);
#pragma unroll
                for (int k = 0; k < 9; ++k) {
                    const float u = w0[c * 9 + k], v = w1[c * 9 + k];
                    a0 = fmaf(xw[k],     u, a0);  c0 = fmaf(xw[k],     v, c0);
                    a1 = fmaf(xw[k + 1], u, a1);  c1 = fmaf(xw[k + 1], v, c1);
                    a2 = fmaf(xw[k + 2], u, a2);  c2 = fmaf(xw[k + 2], v, c2);
                    a3 = fmaf(xw[k + 3], u, a3);  c3 = fmaf(xw[k + 3], v, c3);
                }
            }
            mx0 = fmaxf(mx0, fmaxf(fmaxf(a0, a1), fmaxf(a2, a3)));
            mx1 = fmaxf(mx1, fmaxf(fmaxf(c0, c1), fmaxf(c2, c3)));
            cnt0 += (a0 > 0.f) + (a1 > 0.f) + (a2 > 0.f) + (a3 > 0.f);
            cnt1 += (c0 > 0.f) + (c1 > 0.f) + (c2 > 0.f) + (c3 > 0.f);
        }
    } else if (d == 2) {
        for (int t0 = tlo; t0 < thi; t0 += 4) {
            float a0 = bs0, a1 = bs0, a2 = bs0, a3 = bs0;
            float c0 = bs1, c1 = bs1, c2 = bs1, c3 = bs1;
            const int base = t0 + 56;
#pragma unroll
            for (int c = 0; c < 3; ++c) {
                const float* xc = xb + c * XPAD_C + base;
                float xw[20];
                *(float4*)&xw[0]  = *(const float4*)(xc);
                *(float4*)&xw[4]  = *(const float4*)(xc + 4);
                *(float4*)&xw[8]  = *(const float4*)(xc + 8);
                *(float4*)&xw[12] = *(const float4*)(xc + 12);
                *(float4*)&xw[16] = *(const float4*)(xc + 16);
#pragma unroll
                for (int k = 0; k < 9; ++k) {
                    const float u = w0[c * 9 + k], v = w1[c * 9 + k];
                    a0 = fmaf(xw[2 * k],     u, a0);  c0 = fmaf(xw[2 * k],     v, c0);
                    a1 = fmaf(xw[2 * k + 1], u, a1);  c1 = fmaf(xw[2 * k + 1], v, c1);
                    a2 = fmaf(xw[2 * k + 2], u, a2);  c2 = fmaf(xw[2 * k + 2], v, c2);
                    a3 = fmaf(xw[2 * k + 3], u, a3);  c3 = fmaf(xw[2 * k + 3], v, c3);
                }
            }
            mx0 = fmaxf(mx0, fmaxf(fmaxf(a0, a1), fmaxf(a2, a3)));
            mx1 = fmaxf(mx1, fmaxf(fmaxf(c0, c1), fmaxf(c2, c3)));
            cnt0 += (a0 > 0.f) + (a1 > 0.f) + (a2 > 0.f) + (a3 > 0.f);
            cnt1 += (c0 > 0.f) + (c1 > 0.f) + (c2 > 0.f) + (c3 > 0.f);
        }
    } else {
        for (int t0 = tlo; t0 < thi; t0 += 4) {
            float a0 = bs0, a1 = bs0, a2 = bs0, a3 = bs0;
            float c0 = bs1, c1 = bs1, c2 = bs1, c3 = bs1;
            const int base = t0 + 64 - 4 * d;
#pragma unroll
            for (int c = 0; c < 3; ++c) {
                const float* xc = xb + c * XPAD_C + base;
#pragma unroll
                for (int k = 0; k < 9; ++k) {
                    const float4 xv = *(const float4*)(xc + k * d);
                    const float u = w0[c * 9 + k], v = w1[c * 9 + k];
                    a0 = fmaf(xv.x, u, a0);  c0 = fmaf(xv.x, v, c0);
                    a1 = fmaf(xv.y, u, a1);  c1 = fmaf(xv.y, v, c1);
                    a2 = fmaf(xv.z, u, a2);  c2 = fmaf(xv.z, v, c2);
                    a3 = fmaf(xv.w, u, a3);  c3 = fmaf(xv.w, v, c3);
                }
            }
            mx0 = fmaxf(mx0, fmaxf(fmaxf(a0, a1), fmaxf(a2, a3)));
            mx1 = fmaxf(mx1, fmaxf(fmaxf(c0, c1), fmaxf(c2, c3)));
            cnt0 += (a0 > 0.f) + (a1 > 0.f) + (a2 > 0.f) + (a3 > 0.f);
            cnt1 += (c0 > 0.f) + (c1 > 0.f) + (c2 > 0.f) + (c3 > 0.f);
        }
    }

    // combine the 4 position-chunks across waves
    __shared__ float4 red[4][64];
    red[wv][lane] = make_float4(mx0, mx1, (float)cnt0, (float)cnt1);
    __syncthreads();

    if (tid < 64 && act) {
        const float4 r0 = red[0][lane], r1 = red[1][lane],
                     r2 = red[2][lane], r3 = red[3][lane];
        const float fmx0 = fmaxf(fmaxf(r0.x, r1.x), fmaxf(r2.x, r3.x));
        const float fmx1 = fmaxf(fmaxf(r0.y, r1.y), fmaxf(r2.y, r3.y));
        const float fc0  = r0.z + r1.z + r2.z + r3.z;
        const float fc1  = r0.w + r1.w + r2.w + r3.w;
        float* fb = feat + b * FEAT_DIM + gi * 4000;
        fb[j]               = fmx0;
        fb[j + 1000]        = fmx1;
        fb[2000 + j]        = fc0 * (1.0f / 256.0f);
        fb[2000 + j + 1000] = fc1 * (1.0f / 256.0f);
    }
}

// ---------------------------------------------------------------------------
// Kernel B: fold BN into affine feat_n = feat*g + h
// ---------------------------------------------------------------------------
__launch_bounds__(256)
__global__ void bn_stats(const float* __restrict__ feat,
                         const float* __restrict__ gamma,
                         const float* __restrict__ beta,
                         float* __restrict__ g, float* __restrict__ h)
{
    const int f = blockIdx.x * 256 + threadIdx.x;
    if (f >= FEAT_DIM) return;
    float s = 0.f, ss = 0.f;
#pragma unroll
    for (int b = 0; b < NBATCH; ++b) {
        const float v = feat[b * FEAT_DIM + f];
        s += v;
        ss += v * v;
    }
    const float mu  = s * (1.f / NBATCH);
    const float var = ss * (1.f / NBATCH) - mu * mu;
    const float gg  = gamma[f] * rsqrtf(var + 1e-5f);
    g[f] = gg;
    h[f] = beta[f] - mu * gg;
}

// ---------------------------------------------------------------------------
// Kernel C1: partial GEMV. grid (16 slices, 16 batches); each block reduces
// 1250 features into partial[(b*16+slice)*10 + c].
// ---------------------------------------------------------------------------
__launch_bounds__(256)
__global__ void gemv_partial(const float* __restrict__ feat,
                             const float* __restrict__ g,
                             const float* __restrict__ h,
                             const float* __restrict__ linW,  // (20000,10)
                             float* __restrict__ partial)     // (16,16,10)
{
    const int slice = blockIdx.x;
    const int b     = blockIdx.y;
    const int tid   = threadIdx.x;
    const int f0    = slice * 1250;
    const int f1    = f0 + 1250;

    float acc[10];
#pragma unroll
    for (int c = 0; c < 10; ++c) acc[c] = 0.f;

    for (int f = f0 + tid; f < f1; f += 256) {
        const float t = fmaf(feat[b * FEAT_DIM + f], g[f], h[f]);
#pragma unroll
        for (int c = 0; c < 10; ++c) acc[c] = fmaf(t, linW[f * 10 + c], acc[c]);
    }

#pragma unroll
    for (int c = 0; c < 10; ++c)
#pragma unroll
        for (int o = 32; o > 0; o >>= 1) acc[c] += __shfl_down(acc[c], o, 64);

    __shared__ float red[4][10];
    if ((tid & 63) == 0) {
#pragma unroll
        for (int c = 0; c < 10; ++c) red[tid >> 6][c] = acc[c];
    }
    __syncthreads();
    if (tid < 10)
        partial[(b * 16 + slice) * 10 + tid] =
            red[0][tid] + red[1][tid] + red[2][tid] + red[3][tid];
}

// ---------------------------------------------------------------------------
// Kernel C2: final reduce over slices + bias. 1 block, 160 threads.
// ---------------------------------------------------------------------------
__launch_bounds__(160)
__global__ void gemv_final(const float* __restrict__ partial,
                           const float* __restrict__ linB,
                           float* __restrict__ out)
{
    const int tid = threadIdx.x;       // 0..159
    const int b   = tid / 10;
    const int c   = tid - b * 10;
    float s = linB[c];
#pragma unroll
    for (int sl = 0; sl < 16; ++sl) s += partial[(b * 16 + sl) * 10 + c];
    out[tid] = s;
}

// ---------------------------------------------------------------------------
extern "C" void kernel_launch(void* const* d_in, const int* in_sizes, int n_in,
                              void* d_out, int out_size, void* d_ws, size_t ws_size,
                              hipStream_t stream) {
    const float* x     = (const float*)d_in[0];
    const float* Wk    = (const float*)d_in[1];
    const float* bias  = (const float*)d_in[2];
    const float* gamma = (const float*)d_in[3];
    const float* beta  = (const float*)d_in[4];
    const float* linW  = (const float*)d_in[5];
    const float* linB  = (const float*)d_in[6];
    float* out = (float*)d_out;

    float* feat    = (float*)d_ws;                     // 16*20000
    float* g       = feat + NBATCH * FEAT_DIM;         // 20000
    float* h       = g + FEAT_DIM;                     // 20000
    float* xpad    = h + FEAT_DIM;                     // 16*3*384
    float* partial = xpad + NBATCH * 3 * XPAD_C;       // 16*16*10

    prepad<<<dim3(NBATCH), 256, 0, stream>>>(x, xpad);
    rocket_feat<<<dim3(80, NBATCH), 256, 0, stream>>>(xpad, Wk, bias, feat);
    bn_stats<<<dim3((FEAT_DIM + 255) / 256), 256, 0, stream>>>(feat, gamma, beta, g, h);
    gemv_partial<<<dim3(16, NBATCH), 256, 0, stream>>>(feat, g, h, linW, partial);
    gemv_final<<<dim3(1), 160, 0, stream>>>(partial, linB, out);
}

// Round 5
// 40.017 us; speedup vs baseline: 2.5916x; 1.7205x over previous
//
#include <hip/hip_runtime.h>
#include <cmath>

#define NK       10000
#define GROUP    2000
#define SEQ_L    256
#define FEAT_DIM 20000
#define NBATCH   16

// ---------------------------------------------------------------------------
// Kernel A: dilated conv features via de-interleaved stream buffer in LDS.
//   For dilation d, positions t = r + m*d (streams r=0..d-1) are a DENSE
//   9-tap conv over xs[c][r][*]:  y[m] = b + sum_k w[k] * xs[c][r][m+k],
//   where xs[c][r][u] = x[b, r+(u-4)*d, c]  (zero outside), Mlen = 256/d+8.
//   An 8-position window needs 16 contiguous floats = 4 ds_read_b128/channel.
// Block = 256 threads (4 waves). Lane owns kernel pair (n0=gi*2000+j,
// n1=n0+1000). Wave wv processes 8 of the 32 (r,m0) windows; 4 KB LDS
// combine merges max/count across waves.  grid = (80, 16).
// ---------------------------------------------------------------------------
__launch_bounds__(256)
__global__ void rocket_feat(const float* __restrict__ x_enc,  // (16,256,3)
                            const float* __restrict__ Wk,     // (10000,3,9)
                            const float* __restrict__ bias,   // (10000,)
                            float* __restrict__ feat)         // (16,20000)
{
    __shared__ __align__(16) float xs[1152];   // 3 * (256 + 8d) floats, max d=16
    __shared__ float4 red[4][64];

    const int gi   = blockIdx.x >> 4;          // dilation group 0..4
    const int sb   = blockIdx.x & 15;          // sub-block 0..15
    const int b    = blockIdx.y;
    const int d    = 1 << gi;
    const int Mlen = (SEQ_L >> gi) + 8;        // 264,136,72,40,24 (all %4==0)
    const int tid  = threadIdx.x;
    const int lane = tid & 63;
    const int wv   = __builtin_amdgcn_readfirstlane(tid >> 6);   // 0..3 uniform

    // ---- stage de-interleaved padded streams into LDS ----
    const int dml = d * Mlen;                  // floats per channel
    for (int idx = tid; idx < 3 * dml; idx += 256) {
        const int c  = idx / dml;
        const int rm = idx - c * dml;
        const int r  = rm / Mlen;
        const int u  = rm - r * Mlen;
        const int t  = r + (u - 4) * d;
        xs[idx] = (t >= 0 && t < SEQ_L) ? x_enc[(b * SEQ_L + t) * 3 + c] : 0.f;
    }

    const int j    = sb * 64 + lane;           // 0..1023 (active if <1000)
    const bool act = (j < 1000);
    const int jj   = act ? j : 0;
    const int n0   = gi * GROUP + jj;
    const int n1   = n0 + 1000;

    float w0[27], w1[27];
#pragma unroll
    for (int q = 0; q < 27; ++q) { w0[q] = Wk[n0 * 27 + q]; w1[q] = Wk[n1 * 27 + q]; }
    const float bs0 = bias[n0];
    const float bs1 = bias[n1];

    __syncthreads();

    float mx0 = -INFINITY, mx1 = -INFINITY;
    float cnt0 = 0.f, cnt1 = 0.f;

    const int mask = (32 >> gi) - 1;           // windows per stream - 1
    const int rsh  = 5 - gi;                   // om >> rsh = stream index

#pragma unroll
    for (int i = 0; i < 8; ++i) {
        const int om = wv * 8 + i;             // window id 0..31 (uniform)
        const int r  = om >> rsh;              // stream
        const int m0 = (om & mask) << 3;       // first position-in-stream

        float a[8], e[8];
#pragma unroll
        for (int p = 0; p < 8; ++p) { a[p] = bs0; e[p] = bs1; }

#pragma unroll
        for (int c = 0; c < 3; ++c) {
            const float* xc = &xs[(c * d + r) * Mlen + m0];
            float xw[16];
            *(float4*)&xw[0]  = *(const float4*)(xc);
            *(float4*)&xw[4]  = *(const float4*)(xc + 4);
            *(float4*)&xw[8]  = *(const float4*)(xc + 8);
            *(float4*)&xw[12] = *(const float4*)(xc + 12);
#pragma unroll
            for (int k = 0; k < 9; ++k) {
                const float u = w0[c * 9 + k], v = w1[c * 9 + k];
#pragma unroll
                for (int p = 0; p < 8; ++p) {
                    a[p] = fmaf(xw[p + k], u, a[p]);
                    e[p] = fmaf(xw[p + k], v, e[p]);
                }
            }
        }
#pragma unroll
        for (int p = 0; p < 8; ++p) {
            mx0 = fmaxf(mx0, a[p]);  mx1 = fmaxf(mx1, e[p]);
            cnt0 += (a[p] > 0.f) ? 1.f : 0.f;
            cnt1 += (e[p] > 0.f) ? 1.f : 0.f;
        }
    }

    // ---- combine the 4 waves' window-sets ----
    red[wv][lane] = make_float4(mx0, mx1, cnt0, cnt1);
    __syncthreads();

    if (tid < 64 && act) {
        const float4 r0 = red[0][lane], r1 = red[1][lane],
                     r2 = red[2][lane], r3 = red[3][lane];
        const float fmx0 = fmaxf(fmaxf(r0.x, r1.x), fmaxf(r2.x, r3.x));
        const float fmx1 = fmaxf(fmaxf(r0.y, r1.y), fmaxf(r2.y, r3.y));
        const float fc0  = r0.z + r1.z + r2.z + r3.z;
        const float fc1  = r0.w + r1.w + r2.w + r3.w;
        float* fb = feat + b * FEAT_DIM + gi * 4000;
        fb[j]               = fmx0;
        fb[j + 1000]        = fmx1;
        fb[2000 + j]        = fc0 * (1.0f / 256.0f);
        fb[2000 + j + 1000] = fc1 * (1.0f / 256.0f);
    }
}

// ---------------------------------------------------------------------------
// Kernel B: fold BN into affine feat_n = feat*g + h
// ---------------------------------------------------------------------------
__launch_bounds__(256)
__global__ void bn_stats(const float* __restrict__ feat,
                         const float* __restrict__ gamma,
                         const float* __restrict__ beta,
                         float* __restrict__ g, float* __restrict__ h)
{
    const int f = blockIdx.x * 256 + threadIdx.x;
    if (f >= FEAT_DIM) return;
    float s = 0.f, ss = 0.f;
#pragma unroll
    for (int b = 0; b < NBATCH; ++b) {
        const float v = feat[b * FEAT_DIM + f];
        s += v;
        ss += v * v;
    }
    const float mu  = s * (1.f / NBATCH);
    const float var = ss * (1.f / NBATCH) - mu * mu;
    const float gg  = gamma[f] * rsqrtf(var + 1e-5f);
    g[f] = gg;
    h[f] = beta[f] - mu * gg;
}

// ---------------------------------------------------------------------------
// Kernel C1: partial GEMV. grid (16 slices, 16 batches).
// ---------------------------------------------------------------------------
__launch_bounds__(256)
__global__ void gemv_partial(const float* __restrict__ feat,
                             const float* __restrict__ g,
                             const float* __restrict__ h,
                             const float* __restrict__ linW,  // (20000,10)
                             float* __restrict__ partial)     // (16,16,10)
{
    const int slice = blockIdx.x;
    const int b     = blockIdx.y;
    const int tid   = threadIdx.x;
    const int f0    = slice * 1250;
    const int f1    = f0 + 1250;

    float acc[10];
#pragma unroll
    for (int c = 0; c < 10; ++c) acc[c] = 0.f;

    for (int f = f0 + tid; f < f1; f += 256) {
        const float t = fmaf(feat[b * FEAT_DIM + f], g[f], h[f]);
#pragma unroll
        for (int c = 0; c < 10; ++c) acc[c] = fmaf(t, linW[f * 10 + c], acc[c]);
    }

#pragma unroll
    for (int c = 0; c < 10; ++c)
#pragma unroll
        for (int o = 32; o > 0; o >>= 1) acc[c] += __shfl_down(acc[c], o, 64);

    __shared__ float red[4][10];
    if ((tid & 63) == 0) {
#pragma unroll
        for (int c = 0; c < 10; ++c) red[tid >> 6][c] = acc[c];
    }
    __syncthreads();
    if (tid < 10)
        partial[(b * 16 + slice) * 10 + tid] =
            red[0][tid] + red[1][tid] + red[2][tid] + red[3][tid];
}

// ---------------------------------------------------------------------------
// Kernel C2: final reduce over slices + bias. 1 block, 160 threads.
// ---------------------------------------------------------------------------
__launch_bounds__(160)
__global__ void gemv_final(const float* __restrict__ partial,
                           const float* __restrict__ linB,
                           float* __restrict__ out)
{
    const int tid = threadIdx.x;       // 0..159
    const int b   = tid / 10;
    const int c   = tid - b * 10;
    float s = linB[c];
#pragma unroll
    for (int sl = 0; sl < 16; ++sl) s += partial[(b * 16 + sl) * 10 + c];
    out[tid] = s;
}

// ---------------------------------------------------------------------------
extern "C" void kernel_launch(void* const* d_in, const int* in_sizes, int n_in,
                              void* d_out, int out_size, void* d_ws, size_t ws_size,
                              hipStream_t stream) {
    const float* x     = (const float*)d_in[0];
    const float* Wk    = (const float*)d_in[1];
    const float* bias  = (const float*)d_in[2];
    const float* gamma = (const float*)d_in[3];
    const float* beta  = (const float*)d_in[4];
    const float* linW  = (const float*)d_in[5];
    const float* linB  = (const float*)d_in[6];
    float* out = (float*)d_out;

    float* feat    = (float*)d_ws;                     // 16*20000
    float* g       = feat + NBATCH * FEAT_DIM;         // 20000
    float* h       = g + FEAT_DIM;                     // 20000
    float* partial = h + FEAT_DIM;                     // 16*16*10

    rocket_feat<<<dim3(80, NBATCH), 256, 0, stream>>>(x, Wk, bias, feat);
    bn_stats<<<dim3((FEAT_DIM + 255) / 256), 256, 0, stream>>>(feat, gamma, beta, g, h);
    gemv_partial<<<dim3(16, NBATCH), 256, 0, stream>>>(feat, g, h, linW, partial);
    gemv_final<<<dim3(1), 160, 0, stream>>>(partial, linB, out);
}